// Round 5
// baseline (251.421 us; speedup 1.0000x reference)
//
#include <hip/hip_runtime.h>
#include <hip/hip_bf16.h>

typedef __attribute__((ext_vector_type(4))) int i32x4;

#define M_DIM 8192
#define N_DIM 8192
#define K_DIM 2048
#define WCOUNT (N_DIM * K_DIM)

// ---------------- kernel 1: per-block partial sums of |w| ----------------
__global__ __launch_bounds__(256) void k_abs_partial(const float* __restrict__ w,
                                                     float* __restrict__ part) {
    int tid = blockIdx.x * 256 + threadIdx.x;
    const float4* w4 = (const float4*)w;
    float s = 0.0f;
    const int total4 = WCOUNT / 4;
    for (int i = tid; i < total4; i += 2048 * 256) {
        float4 v = w4[i];
        s += fabsf(v.x) + fabsf(v.y) + fabsf(v.z) + fabsf(v.w);
    }
    #pragma unroll
    for (int off = 1; off < 64; off <<= 1) s += __shfl_xor(s, off);
    __shared__ float red[4];
    if ((threadIdx.x & 63) == 0) red[threadIdx.x >> 6] = s;
    __syncthreads();
    if (threadIdx.x == 0)
        part[blockIdx.x] = (red[0] + red[1]) + (red[2] + red[3]);
}

// ---------------- kernel 2: deterministic final reduce -> sum|w| ----------------
__global__ __launch_bounds__(256) void k_abs_final(const float* __restrict__ part,
                                                   float* __restrict__ sum) {
    int t = threadIdx.x;
    float s = 0.0f;
    #pragma unroll
    for (int i = 0; i < 8; i++) s += part[t + i * 256];
    #pragma unroll
    for (int off = 1; off < 64; off <<= 1) s += __shfl_xor(s, off);
    __shared__ float red[4];
    if ((t & 63) == 0) red[t >> 6] = s;
    __syncthreads();
    if (t == 0) sum[0] = (red[0] + red[1]) + (red[2] + red[3]);
}

// ---------------- kernel 3: ternary weight quant -> int8 {-1,0,1} ----------------
__global__ __launch_bounds__(256) void k_wquant(const float* __restrict__ w,
                                                const float* __restrict__ sum,
                                                unsigned int* __restrict__ wq) {
    const float thr = 0.5f * (sum[0] * (1.0f / 16777216.0f));
    int tid = blockIdx.x * 256 + threadIdx.x;
    const float4* w4 = (const float4*)w;
    const int total4 = WCOUNT / 4;
    for (int i = tid; i < total4; i += 2048 * 256) {
        float4 v = w4[i];
        union { signed char c[4]; unsigned int u; } q;
        q.c[0] = v.x > thr ? 1 : (v.x < -thr ? -1 : 0);
        q.c[1] = v.y > thr ? 1 : (v.y < -thr ? -1 : 0);
        q.c[2] = v.z > thr ? 1 : (v.z < -thr ? -1 : 0);
        q.c[3] = v.w > thr ? 1 : (v.w < -thr ? -1 : 0);
        wq[i] = q.u;
    }
}

// ---------------- kernel 4: per-row activation quant -> int8 + scale ----------------
__global__ __launch_bounds__(256) void k_xquant(const float* __restrict__ x,
                                                signed char* __restrict__ xq,
                                                float* __restrict__ scale) {
    const int row = blockIdx.x;
    const int t = threadIdx.x;
    const float4* xr = (const float4*)(x + (size_t)row * K_DIM);
    float4 a = xr[t * 2];
    float4 b = xr[t * 2 + 1];
    float m = fmaxf(fmaxf(fmaxf(fabsf(a.x), fabsf(a.y)), fmaxf(fabsf(a.z), fabsf(a.w))),
                    fmaxf(fmaxf(fabsf(b.x), fabsf(b.y)), fmaxf(fabsf(b.z), fabsf(b.w))));
    #pragma unroll
    for (int off = 1; off < 64; off <<= 1) m = fmaxf(m, __shfl_xor(m, off));
    __shared__ float red[4];
    if ((t & 63) == 0) red[t >> 6] = m;
    __syncthreads();
    m = fmaxf(fmaxf(red[0], red[1]), fmaxf(red[2], red[3]));
    const float sc = fmaxf(m, 1e-5f);
    if (t == 0) scale[row] = sc;
    const float r = 127.0f / sc;
    float q[8] = {a.x, a.y, a.z, a.w, b.x, b.y, b.z, b.w};
    union { signed char c[8]; uint2 v; } pk;
    #pragma unroll
    for (int j = 0; j < 8; j++) {
        float v = rintf(q[j] * r);
        v = fminf(fmaxf(v, -127.0f), 127.0f);
        pk.c[j] = (signed char)v;
    }
    *(uint2*)(xq + (size_t)row * K_DIM + t * 8) = pk.v;
}

// ---------------- kernel 5: 256x256 i8 GEMM, BK=64, 4-buffer ring ----------------
// 512 thr / 8 waves (2Mx4N). LDS 128 KiB = 4 buffers x (A 16K + B 16K); buffer b
// holds K-tile kt with kt%4==b (256 rows x 64 B each matrix). Swizzle: 16B slot s
// of row r holds global chunk g = s ^ ((r>>1)&3) (involution; inverse-swizzled
// global source, linear LDS dest, swizzled ds_read — rule 21; worst 2-way = free).
// Per K-tile 2 phases; phase = { stage 2xGLDS(kt+3) | 6 ds_reads for kt+1 into
// alternate reg set | lgkmcnt(6) (forces prev-phase reads; current 6 fly under
// MFMA) | 16 MFMA | [phB only: vmcnt(4) gating kt+2] | s_barrier }.
// Ledger: restage of buf b (as kt+4) at phA(kt+1) is >=2 barriers after all waves'
// lgkm-forced last reads of b (phA(kt)); reads of buf(kt+1) at phA(kt) follow the
// vmcnt(4)+BAR at phB(kt-1) that collectively gates kt+1's stages (lead 4 phases).
#define GLDS16(g, l)                                                                   \
    __builtin_amdgcn_global_load_lds((const __attribute__((address_space(1))) void*)(g), \
                                     (__attribute__((address_space(3))) void*)(l), 16, 0, 0)

#define BAR __builtin_amdgcn_s_barrier()
#define LGKM6 do { asm volatile("s_waitcnt lgkmcnt(6)" ::: "memory"); __builtin_amdgcn_sched_barrier(0); } while (0)
#define LGKM0 do { asm volatile("s_waitcnt lgkmcnt(0)" ::: "memory"); __builtin_amdgcn_sched_barrier(0); } while (0)
#define VMCNT4 do { asm volatile("s_waitcnt vmcnt(4)" ::: "memory"); __builtin_amdgcn_sched_barrier(0); } while (0)
#define VMCNT0 do { asm volatile("s_waitcnt vmcnt(0)" ::: "memory"); __builtin_amdgcn_sched_barrier(0); } while (0)

__global__ __launch_bounds__(512, 2) void k_gemm(const signed char* __restrict__ Aq,
                                                 const signed char* __restrict__ Bq,
                                                 const float* __restrict__ scale,
                                                 const float* __restrict__ sum,
                                                 float* __restrict__ out) {
    __shared__ signed char smem[131072];

    const int t = threadIdx.x;
    const int lane = t & 63;
    const int wid = t >> 6;        // 0..7
    const int wm = wid >> 2;       // 0..1  (M half)
    const int wn = wid & 3;        // 0..3  (N quarter)
    const int lane4 = lane & 15;
    const int hi = lane >> 4;

    // L2-aware mapping: XCD x owns brows [4x,4x+4); 4x4 supertiles sweep bcol.
    const int bid = blockIdx.x;
    const int xcd = bid & 7;
    const int s_ = bid >> 3;
    const int scol = s_ >> 4;
    const int w_ = s_ & 15;
    const int brow = xcd * 4 + (w_ >> 2);
    const int bcol = scol * 4 + (w_ & 3);

    // staging: thread t covers LDS chunk (row=t>>2, slot=t&3) of a 128-row half;
    // fetches global chunk g = (t&3)^((t>>3)&3) (inverse swizzle).
    const int g_ = ((t & 3) ^ ((t >> 3) & 3)) << 4;
    const size_t sa0 = (size_t)(t >> 2) * K_DIM + g_;           // rows 0..127
    const size_t sa1 = (size_t)(128 + (t >> 2)) * K_DIM + g_;   // rows 128..255
    const int dst0 = wid * 1024;          // + lane*16 implicit (wave-uniform base)
    const int dst1 = wid * 1024 + 8192;

    const signed char* Abase = Aq + (size_t)(brow * 256) * K_DIM;
    const signed char* Bbase = Bq + (size_t)(bcol * 256) * K_DIM;

#define STG_A(buf, kt) do {                                                      \
        GLDS16(Abase + (size_t)(kt) * 64 + sa0, smem + (buf) * 32768 + dst0);    \
        GLDS16(Abase + (size_t)(kt) * 64 + sa1, smem + (buf) * 32768 + dst1); } while (0)
#define STG_B(buf, kt) do {                                                      \
        GLDS16(Bbase + (size_t)(kt) * 64 + sa0, smem + (buf) * 32768 + 16384 + dst0); \
        GLDS16(Bbase + (size_t)(kt) * 64 + sa1, smem + (buf) * 32768 + 16384 + dst1); } while (0)

    // fragment reads: A row = wm*128 + m*16 + lane4, B row = wn*64 + n*16 + lane4;
    // k-slot hi, swizzled slot = hi ^ ((lane4>>1)&3) (fragment-invariant).
    const int swz = (hi ^ ((lane4 >> 1) & 3)) << 4;
    const int aRd = (wm * 128 + lane4) * 64 + swz;
    const int bRd = 16384 + (wn * 64 + lane4) * 64 + swz;

    i32x4 acc[8][4];
    #pragma unroll
    for (int m = 0; m < 8; m++)
        #pragma unroll
        for (int n = 0; n < 4; n++) acc[m][n] = (i32x4){0, 0, 0, 0};
    i32x4 fa[2][8], fb[2][4];

#define RD_FB(s, buf) do { _Pragma("unroll") for (int n_ = 0; n_ < 4; n_++)      \
        fb[s][n_] = *(const i32x4*)&smem[(buf) * 32768 + bRd + n_ * 1024]; } while (0)
#define RD_FA01(s, buf) do { _Pragma("unroll") for (int m_ = 0; m_ < 2; m_++)    \
        fa[s][m_] = *(const i32x4*)&smem[(buf) * 32768 + aRd + m_ * 1024]; } while (0)
#define RD_FA27(s, buf) do { _Pragma("unroll") for (int m_ = 2; m_ < 8; m_++)    \
        fa[s][m_] = *(const i32x4*)&smem[(buf) * 32768 + aRd + m_ * 1024]; } while (0)
#define MMQ(s, mlo) do { __builtin_amdgcn_s_setprio(1);                          \
        _Pragma("unroll") for (int m_ = 0; m_ < 4; m_++)                         \
        _Pragma("unroll") for (int n_ = 0; n_ < 4; n_++)                         \
            acc[(mlo) + m_][n_] = __builtin_amdgcn_mfma_i32_16x16x64_i8(         \
                fa[s][(mlo) + m_], fb[s][n_], acc[(mlo) + m_][n_], 0, 0, 0);     \
        __builtin_amdgcn_s_setprio(0); __builtin_amdgcn_sched_barrier(0); } while (0)

    // ---- prologue: stage kt0,kt1,kt2 (12 loads); gate kt0+kt1; preload kt0 frags
    STG_A(0, 0); STG_B(0, 0);
    STG_A(1, 1); STG_B(1, 1);
    STG_A(2, 2); STG_B(2, 2);
    VMCNT4;      // kt0,kt1 landed; kt2's 4 in flight
    BAR;
    RD_FB(0, 0); RD_FA01(0, 0); RD_FA27(0, 0);   // 12 reads, forced by first LGKM6

    // ---- main loop: i=0..6, kt=4i..4i+3 (phases: stage kt+3, read kt+1, MFMA kt)
    #pragma unroll 1
    for (int i = 0; i < 7; i++) {
        const int kt = 4 * i;
        // q=0 (buf0; next buf1; stage buf3; s=0, sp=1)
        STG_A(3, kt + 3); RD_FB(1, 1); RD_FA01(1, 1); LGKM6; MMQ(0, 0); BAR;
        STG_B(3, kt + 3); RD_FA27(1, 1);              LGKM6; MMQ(0, 4); VMCNT4; BAR;
        // q=1 (buf1; next buf2; stage buf0; s=1, sp=0)
        STG_A(0, kt + 4); RD_FB(0, 2); RD_FA01(0, 2); LGKM6; MMQ(1, 0); BAR;
        STG_B(0, kt + 4); RD_FA27(0, 2);              LGKM6; MMQ(1, 4); VMCNT4; BAR;
        // q=2 (buf2; next buf3; stage buf1; s=0, sp=1)
        STG_A(1, kt + 5); RD_FB(1, 3); RD_FA01(1, 3); LGKM6; MMQ(0, 0); BAR;
        STG_B(1, kt + 5); RD_FA27(1, 3);              LGKM6; MMQ(0, 4); VMCNT4; BAR;
        // q=3 (buf3; next buf0; stage buf2; s=1, sp=0)
        STG_A(2, kt + 6); RD_FB(0, 0); RD_FA01(0, 0); LGKM6; MMQ(1, 0); BAR;
        STG_B(2, kt + 6); RD_FA27(0, 0);              LGKM6; MMQ(1, 4); VMCNT4; BAR;
    }

    // ---- peel i=7: kt28..31 (stages only kt31; gates kt30 then kt31)
    // kt28 (buf0, next buf1, stage buf3)
    STG_A(3, 31); RD_FB(1, 1); RD_FA01(1, 1); LGKM6; MMQ(0, 0); BAR;
    STG_B(3, 31); RD_FA27(1, 1);              LGKM6; MMQ(0, 4); VMCNT4; BAR;
    // kt29 (buf1, next buf2)
    RD_FB(0, 2); RD_FA01(0, 2); LGKM6; MMQ(1, 0); BAR;
    RD_FA27(0, 2);              LGKM6; MMQ(1, 4); VMCNT0; BAR;
    // kt30 (buf2, next buf3)
    RD_FB(1, 3); RD_FA01(1, 3); LGKM6; MMQ(0, 0); BAR;
    RD_FA27(1, 3);              LGKM6; MMQ(0, 4); BAR;
    // kt31 (buf3)
    LGKM0; MMQ(1, 0); MMQ(1, 4);

    // ---- epilogue: out = (max(acc * w_scale / scale_row, 0))^2
    const float wsc = sum[0] * (1.0f / 16777216.0f);
    const int rb = brow * 256 + wm * 128 + hi * 4;
    const int cb = bcol * 256 + wn * 64 + lane4;
    #pragma unroll
    for (int m = 0; m < 8; m++) {
        #pragma unroll
        for (int j = 0; j < 4; j++) {
            const int grow = rb + m * 16 + j;
            const float coef = wsc / scale[grow];
            #pragma unroll
            for (int n = 0; n < 4; n++) {
                float v = (float)acc[m][n][j] * coef;   // C/D: col=lane&15, row=hi*4+j
                v = fmaxf(v, 0.0f);
                out[(size_t)grow * N_DIM + cb + n * 16] = v * v;
            }
        }
    }
#undef STG_A
#undef STG_B
#undef RD_FB
#undef RD_FA01
#undef RD_FA27
#undef MMQ
}

// ---------------- launch ----------------
extern "C" void kernel_launch(void* const* d_in, const int* in_sizes, int n_in,
                              void* d_out, int out_size, void* d_ws, size_t ws_size,
                              hipStream_t stream) {
    const float* x = (const float*)d_in[0];   // [4,2048,2048] fp32
    const float* w = (const float*)d_in[1];   // [8192,2048] fp32
    float* out = (float*)d_out;               // [4,2048,8192] fp32

    char* ws = (char*)d_ws;
    float* sum   = (float*)ws;
    float* part  = (float*)(ws + 256);
    float* scale = (float*)(ws + 16384);
    signed char* xq = (signed char*)(ws + 65536);
    signed char* wq = (signed char*)(ws + 65536 + 16777216);

    k_abs_partial<<<2048, 256, 0, stream>>>(w, part);
    k_abs_final<<<1, 256, 0, stream>>>(part, sum);
    k_wquant<<<2048, 256, 0, stream>>>(w, sum, (unsigned int*)wq);
    k_xquant<<<M_DIM, 256, 0, stream>>>(x, xq, scale);
    k_gemm<<<dim3(1024), 512, 0, stream>>>(xq, wq, scale, sum, out);
}

// Round 6
// 199.885 us; speedup vs baseline: 1.2578x; 1.2578x over previous
//
#include <hip/hip_runtime.h>
#include <hip/hip_bf16.h>

typedef __attribute__((ext_vector_type(4))) int i32x4;

#define M_DIM 8192
#define N_DIM 8192
#define K_DIM 2048
#define BK 128                   // i8 K-bytes per K-tile
#define WCOUNT (N_DIM * K_DIM)   // 16,777,216 weight elements

// ---------------- kernel 1: per-block partial sums of |w| ----------------
__global__ __launch_bounds__(256) void k_abs_partial(const float* __restrict__ w,
                                                     float* __restrict__ part) {
    int tid = blockIdx.x * 256 + threadIdx.x;
    const float4* w4 = (const float4*)w;
    float s = 0.0f;
    const int total4 = WCOUNT / 4;
    for (int i = tid; i < total4; i += 2048 * 256) {
        float4 v = w4[i];
        s += fabsf(v.x) + fabsf(v.y) + fabsf(v.z) + fabsf(v.w);
    }
    #pragma unroll
    for (int off = 1; off < 64; off <<= 1) s += __shfl_xor(s, off);
    __shared__ float red[4];
    if ((threadIdx.x & 63) == 0) red[threadIdx.x >> 6] = s;
    __syncthreads();
    if (threadIdx.x == 0)
        part[blockIdx.x] = (red[0] + red[1]) + (red[2] + red[3]);
}

// ---------------- kernel 2: deterministic final reduce -> sum|w| ----------------
__global__ __launch_bounds__(256) void k_abs_final(const float* __restrict__ part,
                                                   float* __restrict__ sum) {
    int t = threadIdx.x;
    float s = 0.0f;
    #pragma unroll
    for (int i = 0; i < 8; i++) s += part[t + i * 256];
    #pragma unroll
    for (int off = 1; off < 64; off <<= 1) s += __shfl_xor(s, off);
    __shared__ float red[4];
    if ((t & 63) == 0) red[t >> 6] = s;
    __syncthreads();
    if (t == 0) sum[0] = (red[0] + red[1]) + (red[2] + red[3]);
}

// ---------------- kernel 3: ternary weight quant -> int8 {-1,0,1} ----------------
__global__ __launch_bounds__(256) void k_wquant(const float* __restrict__ w,
                                                const float* __restrict__ sum,
                                                unsigned int* __restrict__ wq) {
    const float thr = 0.5f * (sum[0] * (1.0f / 16777216.0f));
    int tid = blockIdx.x * 256 + threadIdx.x;
    const float4* w4 = (const float4*)w;
    const int total4 = WCOUNT / 4;
    for (int i = tid; i < total4; i += 2048 * 256) {
        float4 v = w4[i];
        union { signed char c[4]; unsigned int u; } q;
        q.c[0] = v.x > thr ? 1 : (v.x < -thr ? -1 : 0);
        q.c[1] = v.y > thr ? 1 : (v.y < -thr ? -1 : 0);
        q.c[2] = v.z > thr ? 1 : (v.z < -thr ? -1 : 0);
        q.c[3] = v.w > thr ? 1 : (v.w < -thr ? -1 : 0);
        wq[i] = q.u;
    }
}

// ---------------- kernel 4: per-row activation quant -> int8 + scale ----------------
__global__ __launch_bounds__(256) void k_xquant(const float* __restrict__ x,
                                                signed char* __restrict__ xq,
                                                float* __restrict__ scale) {
    const int row = blockIdx.x;
    const int t = threadIdx.x;
    const float4* xr = (const float4*)(x + (size_t)row * K_DIM);
    float4 a = xr[t * 2];
    float4 b = xr[t * 2 + 1];
    float m = fmaxf(fmaxf(fmaxf(fabsf(a.x), fabsf(a.y)), fmaxf(fabsf(a.z), fabsf(a.w))),
                    fmaxf(fmaxf(fabsf(b.x), fabsf(b.y)), fmaxf(fabsf(b.z), fabsf(b.w))));
    #pragma unroll
    for (int off = 1; off < 64; off <<= 1) m = fmaxf(m, __shfl_xor(m, off));
    __shared__ float red[4];
    if ((t & 63) == 0) red[t >> 6] = m;
    __syncthreads();
    m = fmaxf(fmaxf(red[0], red[1]), fmaxf(red[2], red[3]));
    const float sc = fmaxf(m, 1e-5f);
    if (t == 0) scale[row] = sc;
    const float r = 127.0f / sc;
    float q[8] = {a.x, a.y, a.z, a.w, b.x, b.y, b.z, b.w};
    union { signed char c[8]; uint2 v; } pk;
    #pragma unroll
    for (int j = 0; j < 8; j++) {
        float v = rintf(q[j] * r);
        v = fminf(fmaxf(v, -127.0f), 127.0f);
        pk.c[j] = (signed char)v;
    }
    *(uint2*)(xq + (size_t)row * K_DIM + t * 8) = pk.v;
}

// ---------------- kernel 5: 256x256 8-phase i8 MFMA GEMM ----------------
// A = x_q [M][K] i8, B = w_q [N][K] i8, out[M][N] fp32 = relu(acc*coef)^2.
// 512 thr / 8 waves (2Mx4N). LDS 128 KiB: 2 buffers x (A 32K + B 32K), half = 128
// rows x 128 B. Swizzle: slot s of row r holds chunk g = s ^ ((r>>1)&7) (inverse-
// swizzled global source, linear LDS dest, swizzled read — rule 21).
// Phase = { 1 STG | ds_reads | BAR | setprio 16xMFMA | BAR }. NO manual lgkm waits
// and NO sched_barrier pins: ds_reads are compiler-visible, so hipcc emits
// fine-grained lgkmcnt(N) interleaving early MFMAs with late reads (m97 behavior;
// m141 showed order-pinning regresses). Counted vmcnt only for global_load_lds
// gating (compiler cannot track LDS-DMA deps); "memory" clobber orders it.
// Stage ring (iter i: buf0=kt2i read ph1-3, buf1=kt2i+1 read ph5-7):
//   ph1: B1h1(kt+1)  ph2: A1h0(kt+1)  ph3: A1h1(kt+1)  ph4: B0h0(kt+2)
//   ph5: B0h1(kt+2)  ph6: A0h0(kt+2)  ph7: A0h1(kt+2)  ph8: B1h0(kt+3)
// vmcnt(2) at end of ph4 (gates buf1 reads at ph5) and ph8 (gates next buf0 reads).
// WAR: every restage issues >=2 barriers after the region's last ds_read is forced
// (compiler lgkm before consuming-MFMA issue, which precedes that phase's barrier).
#define GLDS16(g, l)                                                                   \
    __builtin_amdgcn_global_load_lds((const __attribute__((address_space(1))) void*)(g), \
                                     (__attribute__((address_space(3))) void*)(l), 16, 0, 0)

#define AOFF(b, h) ((b) * 32768 + (h) * 16384)
#define BOFF(b, h) (65536 + (b) * 32768 + (h) * 16384)
#define BAR __builtin_amdgcn_s_barrier()
#define VMCNT2 asm volatile("s_waitcnt vmcnt(2)" ::: "memory")
#define VMCNT0 asm volatile("s_waitcnt vmcnt(0)" ::: "memory")

__global__ __launch_bounds__(512, 2) void k_gemm(const signed char* __restrict__ Aq,
                                                 const signed char* __restrict__ Bq,
                                                 const float* __restrict__ scale,
                                                 const float* __restrict__ sum,
                                                 float* __restrict__ out) {
    __shared__ signed char lds[131072];

    const int t = threadIdx.x;
    const int lane = t & 63;
    const int wid = t >> 6;        // 0..7
    const int wm = wid >> 2;       // 0..1  (M half)
    const int wn = wid & 3;        // 0..3  (N quarter)
    const int lane4 = lane & 15;
    const int hi = lane >> 4;

    // L2-aware mapping: XCD x owns brows [4x,4x+4); 4x4 supertiles sweep bcol.
    const int bid = blockIdx.x;
    const int xcd = bid & 7;
    const int s_ = bid >> 3;
    const int scol = s_ >> 4;
    const int w_ = s_ & 15;
    const int brow = xcd * 4 + (w_ >> 2);
    const int bcol = scol * 4 + (w_ & 3);

    // staging: thread t owns chunk c0=t (rows 0..63) and c1=t+512 (rows 64..127)
    // of a 128-row half-tile; global k-chunk inverse-swizzled.
    const int r0 = t >> 3;
    const int g0 = ((t & 7) ^ ((t >> 4) & 7)) << 4;
    const int g1 = (((t + 512) & 7) ^ (((t + 512) >> 4) & 7)) << 4;
    const int sa0 = r0 * K_DIM + g0;          // + half*128*K_DIM + kt*BK
    const int sa1 = (64 + r0) * K_DIM + g1;
    const int dst0 = wid * 1024;              // + lane*16 implicit
    const int dst1 = wid * 1024 + 8192;

    const signed char* Abase = Aq + (size_t)(brow * 256) * K_DIM;
    const signed char* Bbase = Bq + (size_t)(bcol * 256) * K_DIM;

#define STG(gb, ldsoff, half, kt) do {                                                  \
        GLDS16((gb) + (half) * (128 * K_DIM) + (kt) * BK + sa0, lds + (ldsoff) + dst0); \
        GLDS16((gb) + (half) * (128 * K_DIM) + (kt) * BK + sa1, lds + (ldsoff) + dst1); \
    } while (0)

    // ---- fragment read bases; swizzled slot = (ks*4+hi) ^ (lane4>>1)
    const int swz0 = (hi ^ (lane4 >> 1)) << 4;
    const int swz1 = ((4 + hi) ^ (lane4 >> 1)) << 4;
    const int aB0 = AOFF(0, wm) + lane4 * 128;
    const int aB1 = AOFF(1, wm) + lane4 * 128;
    const int bB0 = BOFF(0, wn >> 1) + ((wn & 1) * 64 + lane4) * 128;
    const int bB1 = BOFF(1, wn >> 1) + ((wn & 1) * 64 + lane4) * 128;

    i32x4 acc[8][4];
    #pragma unroll
    for (int m = 0; m < 8; m++)
        #pragma unroll
        for (int n = 0; n < 4; n++) acc[m][n] = (i32x4){0, 0, 0, 0};
    i32x4 fa0[8], fa1[8], fb0[4], fb1[4];

#define RDA4(mlo, base) do { _Pragma("unroll") for (int m_ = 0; m_ < 4; m_++) {         \
        fa0[(mlo) + m_] = *(const i32x4*)&lds[(base) + ((mlo) + m_) * 2048 + swz0];     \
        fa1[(mlo) + m_] = *(const i32x4*)&lds[(base) + ((mlo) + m_) * 2048 + swz1]; } } while (0)
#define RDB2(nlo, base) do { _Pragma("unroll") for (int n_ = 0; n_ < 2; n_++) {         \
        fb0[(nlo) + n_] = *(const i32x4*)&lds[(base) + ((nlo) + n_) * 2048 + swz0];     \
        fb1[(nlo) + n_] = *(const i32x4*)&lds[(base) + ((nlo) + n_) * 2048 + swz1]; } } while (0)
#define MM(mlo, nlo) do { __builtin_amdgcn_s_setprio(1);                                \
        _Pragma("unroll") for (int m_ = 0; m_ < 4; m_++)                                \
        _Pragma("unroll") for (int n_ = 0; n_ < 2; n_++) {                              \
            acc[(mlo) + m_][(nlo) + n_] = __builtin_amdgcn_mfma_i32_16x16x64_i8(        \
                fa0[(mlo) + m_], fb0[(nlo) + n_], acc[(mlo) + m_][(nlo) + n_], 0, 0, 0);\
            acc[(mlo) + m_][(nlo) + n_] = __builtin_amdgcn_mfma_i32_16x16x64_i8(        \
                fa1[(mlo) + m_], fb1[(nlo) + n_], acc[(mlo) + m_][(nlo) + n_], 0, 0, 0);\
        } __builtin_amdgcn_s_setprio(0); } while (0)

    // ---- prologue: buf0 <- kt0 (B-h0,B-h1,A-h0,A-h1), buf1 B-h0 <- kt1; gate buf0.
    STG(Bbase, BOFF(0, 0), 0, 0);
    STG(Bbase, BOFF(0, 1), 1, 0);
    STG(Abase, AOFF(0, 0), 0, 0);
    STG(Abase, AOFF(0, 1), 1, 0);
    STG(Bbase, BOFF(1, 0), 0, 1);
    VMCNT2;
    BAR;

    #pragma unroll 1
    for (int i = 0; i < 8; i++) {
        const int kt = 2 * i;
        // ph1: Q1(buf0) -- reads A0-3, B0-1 (12)
        STG(Bbase, BOFF(1, 1), 1, kt + 1);
        RDA4(0, aB0); RDB2(0, bB0);
        BAR;
        MM(0, 0);
        BAR;
        // ph2: Q3(buf0) -- reads B2-3 (4)
        STG(Abase, AOFF(1, 0), 0, kt + 1);
        RDB2(2, bB0);
        BAR;
        MM(0, 2);
        BAR;
        // ph3: Q2(buf0) -- reads A4-7 (8)
        STG(Abase, AOFF(1, 1), 1, kt + 1);
        RDA4(4, aB0);
        BAR;
        MM(4, 0);
        BAR;
        // ph4: Q4(buf0) -- no reads; gate buf1
        if (i < 7) STG(Bbase, BOFF(0, 0), 0, kt + 2);
        MM(4, 2);
        if (i < 7) VMCNT2; else VMCNT0;
        BAR;
        // ph5: Q1(buf1) -- reads A0-3, B0-1 (12)
        if (i < 7) STG(Bbase, BOFF(0, 1), 1, kt + 2);
        RDA4(0, aB1); RDB2(0, bB1);
        BAR;
        MM(0, 0);
        BAR;
        // ph6: Q3(buf1) -- reads B2-3 (4)
        if (i < 7) STG(Abase, AOFF(0, 0), 0, kt + 2);
        RDB2(2, bB1);
        BAR;
        MM(0, 2);
        BAR;
        // ph7: Q2(buf1) -- reads A4-7 (8)
        if (i < 7) STG(Abase, AOFF(0, 1), 1, kt + 2);
        RDA4(4, aB1);
        BAR;
        MM(4, 0);
        BAR;
        // ph8: Q4(buf1) -- no reads; gate next buf0
        if (i < 7) STG(Bbase, BOFF(1, 0), 0, kt + 3);
        MM(4, 2);
        if (i < 7) VMCNT2;
        BAR;
    }

    // ---- epilogue: out = (max(acc * w_scale / scale_row, 0))^2
    const float wsc = sum[0] * (1.0f / 16777216.0f);
    const int rb = brow * 256 + wm * 128 + hi * 4;
    const int cb = bcol * 256 + wn * 64 + lane4;
    #pragma unroll
    for (int m = 0; m < 8; m++) {
        #pragma unroll
        for (int j = 0; j < 4; j++) {
            const int grow = rb + m * 16 + j;
            const float coef = wsc / scale[grow];
            #pragma unroll
            for (int n = 0; n < 4; n++) {
                float v = (float)acc[m][n][j] * coef;   // C/D: col=lane&15, row=hi*4+j
                v = fmaxf(v, 0.0f);
                out[(size_t)grow * N_DIM + cb + n * 16] = v * v;
            }
        }
    }
#undef STG
#undef RDA4
#undef RDB2
#undef MM
}

// ---------------- launch ----------------
extern "C" void kernel_launch(void* const* d_in, const int* in_sizes, int n_in,
                              void* d_out, int out_size, void* d_ws, size_t ws_size,
                              hipStream_t stream) {
    const float* x = (const float*)d_in[0];   // [4,2048,2048] fp32
    const float* w = (const float*)d_in[1];   // [8192,2048] fp32
    float* out = (float*)d_out;               // [4,2048,8192] fp32

    char* ws = (char*)d_ws;
    float* sum   = (float*)ws;
    float* part  = (float*)(ws + 256);
    float* scale = (float*)(ws + 16384);
    signed char* xq = (signed char*)(ws + 65536);
    signed char* wq = (signed char*)(ws + 65536 + 16777216);

    k_abs_partial<<<2048, 256, 0, stream>>>(w, part);
    k_abs_final<<<1, 256, 0, stream>>>(part, sum);
    k_wquant<<<2048, 256, 0, stream>>>(w, sum, (unsigned int*)wq);
    k_xquant<<<M_DIM, 256, 0, stream>>>(x, xq, scale);
    k_gemm<<<dim3(1024), 512, 0, stream>>>(xq, wq, scale, sum, out);
}

// Round 7
// 198.625 us; speedup vs baseline: 1.2658x; 1.0063x over previous
//
#include <hip/hip_runtime.h>
#include <hip/hip_bf16.h>

typedef __attribute__((ext_vector_type(4))) int i32x4;
typedef __attribute__((ext_vector_type(16))) int i32x16;

#define M_DIM 8192
#define N_DIM 8192
#define K_DIM 2048
#define BK 128                   // i8 K-bytes per K-tile (4 ks-slices of K=32)
#define WCOUNT (N_DIM * K_DIM)

// ---------------- kernel 1: per-block partial sums of |w| ----------------
__global__ __launch_bounds__(256) void k_abs_partial(const float* __restrict__ w,
                                                     float* __restrict__ part) {
    int tid = blockIdx.x * 256 + threadIdx.x;
    const float4* w4 = (const float4*)w;
    float s = 0.0f;
    const int total4 = WCOUNT / 4;
    for (int i = tid; i < total4; i += 2048 * 256) {
        float4 v = w4[i];
        s += fabsf(v.x) + fabsf(v.y) + fabsf(v.z) + fabsf(v.w);
    }
    #pragma unroll
    for (int off = 1; off < 64; off <<= 1) s += __shfl_xor(s, off);
    __shared__ float red[4];
    if ((threadIdx.x & 63) == 0) red[threadIdx.x >> 6] = s;
    __syncthreads();
    if (threadIdx.x == 0)
        part[blockIdx.x] = (red[0] + red[1]) + (red[2] + red[3]);
}

// ---------------- kernel 2: deterministic final reduce -> sum|w| ----------------
__global__ __launch_bounds__(256) void k_abs_final(const float* __restrict__ part,
                                                   float* __restrict__ sum) {
    int t = threadIdx.x;
    float s = 0.0f;
    #pragma unroll
    for (int i = 0; i < 8; i++) s += part[t + i * 256];
    #pragma unroll
    for (int off = 1; off < 64; off <<= 1) s += __shfl_xor(s, off);
    __shared__ float red[4];
    if ((t & 63) == 0) red[t >> 6] = s;
    __syncthreads();
    if (t == 0) sum[0] = (red[0] + red[1]) + (red[2] + red[3]);
}

// ---------------- kernel 3: ternary weight quant -> int8 {-1,0,1} ----------------
__global__ __launch_bounds__(256) void k_wquant(const float* __restrict__ w,
                                                const float* __restrict__ sum,
                                                unsigned int* __restrict__ wq) {
    const float thr = 0.5f * (sum[0] * (1.0f / 16777216.0f));
    int tid = blockIdx.x * 256 + threadIdx.x;
    const float4* w4 = (const float4*)w;
    const int total4 = WCOUNT / 4;
    for (int i = tid; i < total4; i += 2048 * 256) {
        float4 v = w4[i];
        union { signed char c[4]; unsigned int u; } q;
        q.c[0] = v.x > thr ? 1 : (v.x < -thr ? -1 : 0);
        q.c[1] = v.y > thr ? 1 : (v.y < -thr ? -1 : 0);
        q.c[2] = v.z > thr ? 1 : (v.z < -thr ? -1 : 0);
        q.c[3] = v.w > thr ? 1 : (v.w < -thr ? -1 : 0);
        wq[i] = q.u;
    }
}

// ---------------- kernel 4: per-row activation quant -> int8 + scale ----------------
__global__ __launch_bounds__(256) void k_xquant(const float* __restrict__ x,
                                                signed char* __restrict__ xq,
                                                float* __restrict__ scale) {
    const int row = blockIdx.x;
    const int t = threadIdx.x;
    const float4* xr = (const float4*)(x + (size_t)row * K_DIM);
    float4 a = xr[t * 2];
    float4 b = xr[t * 2 + 1];
    float m = fmaxf(fmaxf(fmaxf(fabsf(a.x), fabsf(a.y)), fmaxf(fabsf(a.z), fabsf(a.w))),
                    fmaxf(fmaxf(fabsf(b.x), fabsf(b.y)), fmaxf(fabsf(b.z), fabsf(b.w))));
    #pragma unroll
    for (int off = 1; off < 64; off <<= 1) m = fmaxf(m, __shfl_xor(m, off));
    __shared__ float red[4];
    if ((t & 63) == 0) red[t >> 6] = m;
    __syncthreads();
    m = fmaxf(fmaxf(red[0], red[1]), fmaxf(red[2], red[3]));
    const float sc = fmaxf(m, 1e-5f);
    if (t == 0) scale[row] = sc;
    const float r = 127.0f / sc;
    float q[8] = {a.x, a.y, a.z, a.w, b.x, b.y, b.z, b.w};
    union { signed char c[8]; uint2 v; } pk;
    #pragma unroll
    for (int j = 0; j < 8; j++) {
        float v = rintf(q[j] * r);
        v = fminf(fmaxf(v, -127.0f), 127.0f);
        pk.c[j] = (signed char)v;
    }
    *(uint2*)(xq + (size_t)row * K_DIM + t * 8) = pk.v;
}

// ---------------- kernel 5: 256x256 i8 GEMM, 32x32x32 MFMA, ks-sliced phases ----
// A = x_q [M][K] i8, B = w_q [N][K] i8, out[M][N] fp32 = relu(acc*coef)^2.
// 512 thr / 8 waves (2Mx4N), wave tile 128x64 = 4x2 tiles of 32x32.
// LDS 128 KiB: 2 buffers x (A 32K + B 32K), rows of 128 B. Swizzle: 16B slot s of
// row r holds global chunk g = s ^ ((r>>1)&7) (inverse-swizzled source, linear
// GLDS dest, swizzled ds_read — rule 21; verified 0 conflicts R2-R6).
// Schedule (iter = 2 K-tiles = 8 phases; reads lead MFMA by 1 phase into the
// alternate fragment set; ONLY 2 sync points per iter):
//  ph0: STG_A(b1,kt+1)      R(b0,ks1->s1)  M(s0)
//  ph1:                     R(b0,ks2->s0)  M(s1)
//  ph2:                     R(b0,ks3->s1)  M(s0)  SYNC(lgkm0+vmcnt0+BAR)
//  ph3: STG_B(b0,kt+2)[i<7] R(b1,ks0->s0)  M(s1)
//  ph4: STG_A(b0,kt+2)[i<7] R(b1,ks1->s1)  M(s0)
//  ph5:                     R(b1,ks2->s0)  M(s1)
//  ph6:                     R(b1,ks3->s1)  M(s0)  SYNC
//  ph7: STG_B(b1,kt+3)[i<7] R(b0,ks0->s0)[i<7] M(s1)
// Ledger: stages of a buffer issue >=1 barrier after lgkm0-forced last reads of
// it (WAR); reads of a buffer follow the SYNC whose vmcnt(0) forces its stages,
// with the newest stage 2 phases before the gate (RAW, latency hidden).
#define GLDS16(g, l)                                                                   \
    __builtin_amdgcn_global_load_lds((const __attribute__((address_space(1))) void*)(g), \
                                     (__attribute__((address_space(3))) void*)(l), 16, 0, 0)

#define AOFF(b, h) ((b) * 32768 + (h) * 16384)
#define BOFF(b, h) (65536 + (b) * 32768 + (h) * 16384)
#define SYNC do { asm volatile("s_waitcnt vmcnt(0) lgkmcnt(0)" ::: "memory");          \
        __builtin_amdgcn_sched_barrier(0); __builtin_amdgcn_s_barrier(); } while (0)

__global__ __launch_bounds__(512, 2) void k_gemm(const signed char* __restrict__ Aq,
                                                 const signed char* __restrict__ Bq,
                                                 const float* __restrict__ scale,
                                                 const float* __restrict__ sum,
                                                 float* __restrict__ out) {
    __shared__ signed char lds[131072];

    const int t = threadIdx.x;
    const int lane = t & 63;
    const int wid = t >> 6;        // 0..7
    const int wm = wid >> 2;       // 0..1  (M half: 128 rows)
    const int wn = wid & 3;        // 0..3  (N quarter: 64 cols)
    const int l31 = lane & 31;
    const int kg = lane >> 5;      // k-group for 32x32 operands

    // L2-aware mapping: XCD x owns brows [4x,4x+4); 4x4 supertiles sweep bcol.
    const int bid = blockIdx.x;
    const int xcd = bid & 7;
    const int s_ = bid >> 3;
    const int scol = s_ >> 4;
    const int w_ = s_ & 15;
    const int brow = xcd * 4 + (w_ >> 2);
    const int bcol = scol * 4 + (w_ & 3);

    // staging: thread t covers LDS chunk (row=t>>3, slot=t&7); fetches global
    // chunk g = slot ^ ((row>>1)&7) (inverse swizzle). Batch1 = rows +64.
    const int g_ = ((t & 7) ^ ((t >> 4) & 7)) << 4;
    const size_t sa0 = (size_t)(t >> 3) * K_DIM + g_;
    const size_t sa1 = (size_t)(64 + (t >> 3)) * K_DIM + g_;
    const int dst0 = wid * 1024;          // + lane*16 implicit (wave-uniform base)
    const int dst1 = wid * 1024 + 8192;

    const signed char* Abase = Aq + (size_t)(brow * 256) * K_DIM;
    const signed char* Bbase = Bq + (size_t)(bcol * 256) * K_DIM;

#define STGH(gb, lo) do { GLDS16((gb) + sa0, lds + (lo) + dst0);                  \
                          GLDS16((gb) + sa1, lds + (lo) + dst1); } while (0)
#define STG_A(buf, kt) do { STGH(Abase + (size_t)(kt) * BK, AOFF(buf, 0));        \
        STGH(Abase + 128 * (size_t)K_DIM + (size_t)(kt) * BK, AOFF(buf, 1)); } while (0)
#define STG_B(buf, kt) do { STGH(Bbase + (size_t)(kt) * BK, BOFF(buf, 0));        \
        STGH(Bbase + 128 * (size_t)K_DIM + (size_t)(kt) * BK, BOFF(buf, 1)); } while (0)

    // ---- fragment reads (32x32x32): lane holds op[row=l31][k = kg*16 + 0..15];
    // k-chunk(16B) = ks*2 + kg, swizzled with rswz = ((l31>>1)&7).
    const int rswz = (l31 >> 1) & 7;
    const int ko0 = ((0 * 2 + kg) ^ rswz) << 4;
    const int ko1 = ((1 * 2 + kg) ^ rswz) << 4;
    const int ko2 = ((2 * 2 + kg) ^ rswz) << 4;
    const int ko3 = ((3 * 2 + kg) ^ rswz) << 4;
    const int aB0 = AOFF(0, wm) + l31 * 128;                       // + mt*4096 + ko
    const int aB1 = AOFF(1, wm) + l31 * 128;
    const int bB0 = BOFF(0, wn >> 1) + ((wn & 1) * 64 + l31) * 128; // + nt*4096 + ko
    const int bB1 = BOFF(1, wn >> 1) + ((wn & 1) * 64 + l31) * 128;

    i32x16 acc[4][2];
    #pragma unroll
    for (int m = 0; m < 4; m++)
        #pragma unroll
        for (int n = 0; n < 2; n++)
            acc[m][n] = (i32x16){0,0,0,0,0,0,0,0,0,0,0,0,0,0,0,0};
    i32x4 fA0[4], fB0[2], fA1[4], fB1[2];   // 2 fragment sets (double-buffer)

#define RDS(FA, FB, ab, bb, ko) do {                                              \
        _Pragma("unroll") for (int m_ = 0; m_ < 4; m_++)                          \
            FA[m_] = *(const i32x4*)&lds[(ab) + m_ * 4096 + (ko)];                \
        _Pragma("unroll") for (int n_ = 0; n_ < 2; n_++)                          \
            FB[n_] = *(const i32x4*)&lds[(bb) + n_ * 4096 + (ko)]; } while (0)
#define MMX(FA, FB) do { __builtin_amdgcn_s_setprio(1);                           \
        _Pragma("unroll") for (int m_ = 0; m_ < 4; m_++)                          \
        _Pragma("unroll") for (int n_ = 0; n_ < 2; n_++)                          \
            acc[m_][n_] = __builtin_amdgcn_mfma_i32_32x32x32_i8(                  \
                FA[m_], FB[n_], acc[m_][n_], 0, 0, 0);                            \
        __builtin_amdgcn_s_setprio(0); } while (0)

    // ---- prologue: b0 <- kt0 (all), b1 <- kt1 (B halves); gate b0; preload ks0.
    STG_B(0, 0);
    STG_A(0, 0);
    STG_B(1, 1);
    asm volatile("s_waitcnt vmcnt(4)" ::: "memory");   // b0's 8 landed; b1's 4 fly
    __builtin_amdgcn_sched_barrier(0);
    __builtin_amdgcn_s_barrier();
    RDS(fA0, fB0, aB0, bB0, ko0);

    #pragma unroll 1
    for (int i = 0; i < 8; i++) {
        const int kt = 2 * i;
        // ph0
        STG_A(1, kt + 1);
        RDS(fA1, fB1, aB0, bB0, ko1);
        MMX(fA0, fB0);
        // ph1
        RDS(fA0, fB0, aB0, bB0, ko2);
        MMX(fA1, fB1);
        // ph2
        RDS(fA1, fB1, aB0, bB0, ko3);
        MMX(fA0, fB0);
        SYNC;                                   // b0 reads done; b1 stages landed
        // ph3
        if (i < 7) STG_B(0, kt + 2);
        RDS(fA0, fB0, aB1, bB1, ko0);
        MMX(fA1, fB1);
        // ph4
        if (i < 7) STG_A(0, kt + 2);
        RDS(fA1, fB1, aB1, bB1, ko1);
        MMX(fA0, fB0);
        // ph5
        RDS(fA0, fB0, aB1, bB1, ko2);
        MMX(fA1, fB1);
        // ph6
        RDS(fA1, fB1, aB1, bB1, ko3);
        MMX(fA0, fB0);
        SYNC;                                   // b1 reads done; b0 stages landed
        // ph7
        if (i < 7) {
            STG_B(1, kt + 3);
            RDS(fA0, fB0, aB0, bB0, ko0);
        }
        MMX(fA1, fB1);
    }

    // ---- epilogue: out = (max(acc * w_scale / scale_row, 0))^2
    // 32x32 C/D: col = lane&31, row = (reg&3) + 8*(reg>>2) + 4*(lane>>5)
    const float wsc = sum[0] * (1.0f / 16777216.0f);
    const int rb = brow * 256 + wm * 128 + 4 * kg;
    const int cb = bcol * 256 + wn * 64 + l31;
    #pragma unroll
    for (int m = 0; m < 4; m++) {
        #pragma unroll
        for (int r = 0; r < 16; r++) {
            const int grow = rb + m * 32 + (r & 3) + 8 * (r >> 2);
            const float coef = wsc / scale[grow];
            #pragma unroll
            for (int n = 0; n < 2; n++) {
                float v = (float)acc[m][n][r] * coef;
                v = fmaxf(v, 0.0f);
                out[(size_t)grow * N_DIM + cb + n * 32] = v * v;
            }
        }
    }
#undef STGH
#undef STG_A
#undef STG_B
#undef RDS
#undef MMX
}

// ---------------- launch ----------------
extern "C" void kernel_launch(void* const* d_in, const int* in_sizes, int n_in,
                              void* d_out, int out_size, void* d_ws, size_t ws_size,
                              hipStream_t stream) {
    const float* x = (const float*)d_in[0];   // [4,2048,2048] fp32
    const float* w = (const float*)d_in[1];   // [8192,2048] fp32
    float* out = (float*)d_out;               // [4,2048,8192] fp32

    char* ws = (char*)d_ws;
    float* sum   = (float*)ws;
    float* part  = (float*)(ws + 256);
    float* scale = (float*)(ws + 16384);
    signed char* xq = (signed char*)(ws + 65536);
    signed char* wq = (signed char*)(ws + 65536 + 16777216);

    k_abs_partial<<<2048, 256, 0, stream>>>(w, part);
    k_abs_final<<<1, 256, 0, stream>>>(part, sum);
    k_wquant<<<2048, 256, 0, stream>>>(w, sum, (unsigned int*)wq);
    k_xquant<<<M_DIM, 256, 0, stream>>>(x, xq, scale);
    k_gemm<<<dim3(1024), 512, 0, stream>>>(xq, wq, scale, sum, out);
}